// Round 1
// baseline (112.250 us; speedup 1.0000x reference)
//
#include <hip/hip_runtime.h>
#include <math.h>

#define MAX_GT 128

__global__ __launch_bounds__(256) void rpn_match_kernel(
    const float* __restrict__ anchors,
    const float* __restrict__ deltas,
    const float* __restrict__ gt_boxes,
    float* __restrict__ out,
    int n, int m)
{
    // LDS staging of gt boxes: coords, area, valid mask, full 5-tuple for gather
    __shared__ float sx0[MAX_GT], sy0[MAX_GT], sx1[MAX_GT], sy1[MAX_GT];
    __shared__ float sarea[MAX_GT], smask[MAX_GT];
    __shared__ float sg[MAX_GT][5];

    const int tid = threadIdx.x;
    if (tid < m) {
        float g0 = gt_boxes[tid * 5 + 0];
        float g1 = gt_boxes[tid * 5 + 1];
        float g2 = gt_boxes[tid * 5 + 2];
        float g3 = gt_boxes[tid * 5 + 3];
        float g4 = gt_boxes[tid * 5 + 4];
        sx0[tid] = g0; sy0[tid] = g1; sx1[tid] = g2; sy1[tid] = g3;
        sarea[tid] = (g2 - g0) * (g3 - g1);
        smask[tid] = (g4 != -1.0f) ? 1.0f : 0.0f;
        sg[tid][0] = g0; sg[tid][1] = g1; sg[tid][2] = g2;
        sg[tid][3] = g3; sg[tid][4] = g4;
    }
    __syncthreads();

    const int i = blockIdx.x * 256 + tid;
    if (i >= n) return;

    const float4 a = reinterpret_cast<const float4*>(anchors)[i];
    const float4 d = reinterpret_cast<const float4*>(deltas)[i];

    // ---- proposals (ulp-tolerant path) ----
    const float SCALE_CLAMP = 3.3322045101752038f; // log(224/8)
    float dx = d.x;
    float dy = d.y;
    float dw = fminf(d.z, SCALE_CLAMP);
    float dh = fminf(d.w, SCALE_CLAMP);
    float px = (a.x + a.z) * 0.5f;
    float py = (a.y + a.w) * 0.5f;
    float pw = (a.z - a.x) * 0.5f;
    float ph = (a.w - a.y) * 0.5f;
    float bx = px + pw * dx;
    float by = py + ph * dy;
    float bw = pw * expf(dw);
    float bh = ph * expf(dh);
    float4 prop;
    prop.x = bx - bw;
    prop.y = by - bh;
    prop.z = bx + bw;
    prop.w = by + bh;
    reinterpret_cast<float4*>(out)[i] = prop;

    // ---- IoU max/argmax (bit-faithful path: IEEE fp32, no a*b+c patterns) ----
    const float area1 = (a.z - a.x) * (a.w - a.y);

    float best = -3.0f;  // all m values are >= -1
    int bidx = 0;
    #pragma unroll 4
    for (int j = 0; j < m; ++j) {
        float x1 = fmaxf(a.x, sx0[j]);
        float y1 = fmaxf(a.y, sy0[j]);
        float x2 = fminf(a.z, sx1[j]);
        float y2 = fminf(a.w, sy1[j]);
        float xl = x2 - x1;
        float yl = y2 - y1;
        float inter = ((xl > 0.0f) && (yl > 0.0f)) ? (xl * yl) : 0.0f;
        float uni = (area1 + sarea[j]) - inter;
        float iou = inter / uni;               // precise IEEE fp32 divide
        iou = (smask[j] != 0.0f) ? iou : -1.0f;
        if (iou > best) { best = iou; bidx = j; }   // strict > = first-occurrence argmax
    }

    // ---- classification + gather ----
    const float IOU_LOW = 0.3f, IOU_HIGH = 0.6f, NEUTRAL = -100000000.0f;
    float o0, o1, o2, o3, o4;
    if (best <= IOU_LOW) {
        o0 = o1 = o2 = o3 = o4 = -1.0f;
    } else if (best < IOU_HIGH) {
        o0 = o1 = o2 = o3 = o4 = NEUTRAL;
    } else {
        o0 = sg[bidx][0]; o1 = sg[bidx][1]; o2 = sg[bidx][2];
        o3 = sg[bidx][3]; o4 = sg[bidx][4];
    }
    float* mo = out + (size_t)n * 4 + (size_t)i * 5;
    mo[0] = o0; mo[1] = o1; mo[2] = o2; mo[3] = o3; mo[4] = o4;
}

extern "C" void kernel_launch(void* const* d_in, const int* in_sizes, int n_in,
                              void* d_out, int out_size, void* d_ws, size_t ws_size,
                              hipStream_t stream) {
    const float* anchors  = (const float*)d_in[0];
    const float* deltas   = (const float*)d_in[1];
    const float* gt_boxes = (const float*)d_in[2];
    float* out = (float*)d_out;

    int n = in_sizes[0] / 4;   // 400000
    int m = in_sizes[2] / 5;   // 128

    int nblocks = (n + 255) / 256;
    hipLaunchKernelGGL(rpn_match_kernel, dim3(nblocks), dim3(256), 0, stream,
                       anchors, deltas, gt_boxes, out, n, m);
}

// Round 2
// 94.361 us; speedup vs baseline: 1.1896x; 1.1896x over previous
//
#include <hip/hip_runtime.h>
#include <math.h>

#define MAX_GT 128

__global__ __launch_bounds__(256) void rpn_match_kernel(
    const float* __restrict__ anchors,
    const float* __restrict__ deltas,
    const float* __restrict__ gt_boxes,
    float* __restrict__ out,
    int n, int m)
{
    // gt boxes packed for one ds_read_b128 per j; degenerate box for invalid gt
    __shared__ float4 sbox[MAX_GT];   // (x0,y0,x1,y1) -- also the gather source
    __shared__ float  sarea[MAX_GT];  // gt area (0 for invalid)
    __shared__ float  scls[MAX_GT];   // class id

    const int tid = threadIdx.x;
    if (tid < m) {
        float g0 = gt_boxes[tid * 5 + 0];
        float g1 = gt_boxes[tid * 5 + 1];
        float g2 = gt_boxes[tid * 5 + 2];
        float g3 = gt_boxes[tid * 5 + 3];
        float g4 = gt_boxes[tid * 5 + 4];
        bool valid = (g4 != -1.0f);
        // invalid gt -> degenerate box: inter is always 0, can never win argmax
        sbox[tid] = valid ? make_float4(g0, g1, g2, g3)
                          : make_float4(1e30f, 1e30f, -1e30f, -1e30f);
        sarea[tid] = valid ? (g2 - g0) * (g3 - g1) : 0.0f;
        scls[tid]  = g4;
    }
    __syncthreads();

    // two anchors per thread: i0 and i0+256 (both coalesced)
    const int i0 = blockIdx.x * 512 + tid;
    const int i1 = i0 + 256;
    const bool v0 = (i0 < n);
    const bool v1 = (i1 < n);
    const int i0c = v0 ? i0 : 0;
    const int i1c = v1 ? i1 : 0;

    const float4 a0 = reinterpret_cast<const float4*>(anchors)[i0c];
    const float4 a1 = reinterpret_cast<const float4*>(anchors)[i1c];
    const float4 d0 = reinterpret_cast<const float4*>(deltas)[i0c];
    const float4 d1 = reinterpret_cast<const float4*>(deltas)[i1c];

    // ---- proposals (ulp-tolerant path) ----
    const float SCALE_CLAMP = 3.3322045101752038f; // log(224/8)
    {
        float pw = (a0.z - a0.x) * 0.5f, ph = (a0.w - a0.y) * 0.5f;
        float px = (a0.x + a0.z) * 0.5f, py = (a0.y + a0.w) * 0.5f;
        float bx = px + pw * d0.x, by = py + ph * d0.y;
        float bw = pw * expf(fminf(d0.z, SCALE_CLAMP));
        float bh = ph * expf(fminf(d0.w, SCALE_CLAMP));
        if (v0) reinterpret_cast<float4*>(out)[i0] =
            make_float4(bx - bw, by - bh, bx + bw, by + bh);
    }
    {
        float pw = (a1.z - a1.x) * 0.5f, ph = (a1.w - a1.y) * 0.5f;
        float px = (a1.x + a1.z) * 0.5f, py = (a1.y + a1.w) * 0.5f;
        float bx = px + pw * d1.x, by = py + ph * d1.y;
        float bw = pw * expf(fminf(d1.z, SCALE_CLAMP));
        float bh = ph * expf(fminf(d1.w, SCALE_CLAMP));
        if (v1) reinterpret_cast<float4*>(out)[i1] =
            make_float4(bx - bw, by - bh, bx + bw, by + bh);
    }

    // ---- divide-free IoU argmax ----
    // iou_j > iou_b  <=>  inter_j*(S_b) > inter_b*(S_j), S = area1+area2 > 0
    const float ar0 = (a0.z - a0.x) * (a0.w - a0.y);
    const float ar1 = (a1.z - a1.x) * (a1.w - a1.y);

    float4 b = sbox[0];
    float ga = sarea[0];
    float bI0, bS0, bI1, bS1;
    int bidx0 = 0, bidx1 = 0;
    {
        float xl = fminf(a0.z, b.z) - fmaxf(a0.x, b.x);
        float yl = fminf(a0.w, b.w) - fmaxf(a0.y, b.y);
        bI0 = fmaxf(xl, 0.0f) * fmaxf(yl, 0.0f);
        bS0 = ar0 + ga;
        xl = fminf(a1.z, b.z) - fmaxf(a1.x, b.x);
        yl = fminf(a1.w, b.w) - fmaxf(a1.y, b.y);
        bI1 = fmaxf(xl, 0.0f) * fmaxf(yl, 0.0f);
        bS1 = ar1 + ga;
    }

    #pragma unroll 8
    for (int j = 1; j < m; ++j) {
        b  = sbox[j];
        ga = sarea[j];
        // anchor 0
        {
            float xl = fminf(a0.z, b.z) - fmaxf(a0.x, b.x);
            float yl = fminf(a0.w, b.w) - fmaxf(a0.y, b.y);
            float inter = fmaxf(xl, 0.0f) * fmaxf(yl, 0.0f);
            float S = ar0 + ga;
            bool g = (inter * bS0) > (bI0 * S);   // strict > = first-occurrence argmax
            bI0   = g ? inter : bI0;
            bS0   = g ? S     : bS0;
            bidx0 = g ? j     : bidx0;
        }
        // anchor 1
        {
            float xl = fminf(a1.z, b.z) - fmaxf(a1.x, b.x);
            float yl = fminf(a1.w, b.w) - fmaxf(a1.y, b.y);
            float inter = fmaxf(xl, 0.0f) * fmaxf(yl, 0.0f);
            float S = ar1 + ga;
            bool g = (inter * bS1) > (bI1 * S);
            bI1   = g ? inter : bI1;
            bS1   = g ? S     : bS1;
            bidx1 = g ? j     : bidx1;
        }
    }

    // ---- epilogue: one exact divide per anchor, classify, gather, store ----
    const float IOU_LOW = 0.3f, IOU_HIGH = 0.6f, NEUTRAL = -100000000.0f;
    float* mout = out + (size_t)n * 4;

    {
        float uni = bS0 - bI0;          // fl(fl(a1+a2) - inter): same assoc as ref
        float q = bI0 / uni;            // bit-identical to ref match_quality
        float o0, o1, o2, o3, o4;
        if (q <= IOU_LOW) {
            o0 = o1 = o2 = o3 = o4 = -1.0f;
        } else if (q < IOU_HIGH) {
            o0 = o1 = o2 = o3 = o4 = NEUTRAL;
        } else {
            float4 gbx = sbox[bidx0];
            o0 = gbx.x; o1 = gbx.y; o2 = gbx.z; o3 = gbx.w; o4 = scls[bidx0];
        }
        if (v0) {
            float* mo = mout + (size_t)i0 * 5;
            mo[0] = o0; mo[1] = o1; mo[2] = o2; mo[3] = o3; mo[4] = o4;
        }
    }
    {
        float uni = bS1 - bI1;
        float q = bI1 / uni;
        float o0, o1, o2, o3, o4;
        if (q <= IOU_LOW) {
            o0 = o1 = o2 = o3 = o4 = -1.0f;
        } else if (q < IOU_HIGH) {
            o0 = o1 = o2 = o3 = o4 = NEUTRAL;
        } else {
            float4 gbx = sbox[bidx1];
            o0 = gbx.x; o1 = gbx.y; o2 = gbx.z; o3 = gbx.w; o4 = scls[bidx1];
        }
        if (v1) {
            float* mo = mout + (size_t)i1 * 5;
            mo[0] = o0; mo[1] = o1; mo[2] = o2; mo[3] = o3; mo[4] = o4;
        }
    }
}

extern "C" void kernel_launch(void* const* d_in, const int* in_sizes, int n_in,
                              void* d_out, int out_size, void* d_ws, size_t ws_size,
                              hipStream_t stream) {
    const float* anchors  = (const float*)d_in[0];
    const float* deltas   = (const float*)d_in[1];
    const float* gt_boxes = (const float*)d_in[2];
    float* out = (float*)d_out;

    int n = in_sizes[0] / 4;   // 400000
    int m = in_sizes[2] / 5;   // 128

    int nblocks = (n + 511) / 512;   // 2 anchors per thread
    hipLaunchKernelGGL(rpn_match_kernel, dim3(nblocks), dim3(256), 0, stream,
                       anchors, deltas, gt_boxes, out, n, m);
}